// Round 14
// baseline (316.823 us; speedup 1.0000x reference)
//
#include <hip/hip_runtime.h>
#include <cstdint>

#define B_ 2
#define S_ 2048
#define D_ 1024
#define H_ 16
#define DH_ 64
#define FF_ 4096
#define M_TOK (B_ * S_)  // 4096 token rows

typedef __attribute__((ext_vector_type(8))) short short8;
typedef __attribute__((ext_vector_type(4))) float f32x4;
typedef __attribute__((ext_vector_type(4))) unsigned short us4;

typedef unsigned short u16;

#define SCL 0.18033688011112042f /* 0.125 * log2(e), folded into Q at QKV epilogue */

__device__ __forceinline__ float bf2f(u16 u) {
  union { uint32_t u; float f; } x;
  x.u = ((uint32_t)u) << 16;
  return x.f;
}
__device__ __forceinline__ u16 f2bf(float f) {
  union { float f; uint32_t u; } x;
  x.f = f;
  uint32_t r = x.u + 0x7FFFu + ((x.u >> 16) & 1u);  // RNE
  return (u16)(r >> 16);
}

// pack two f32 -> u32 of two bf16 (lo=a, hi=b); round-half-up (values positive here).
__device__ __forceinline__ uint32_t pack2bf(float a, float b) {
  union { float f; uint32_t u; } x, y;
  x.f = a; y.f = b;
#if __has_builtin(__builtin_amdgcn_perm)
  // v_perm_b32: S0=hi-src, S1=lo-src; sel bytes {7,6,3,2} = {b.b3,b.b2,a.b3,a.b2}
  return __builtin_amdgcn_perm(y.u + 0x8000u, x.u + 0x8000u, 0x07060302u);
#else
  return ((x.u + 0x8000u) >> 16) | ((y.u + 0x8000u) & 0xFFFF0000u);
#endif
}

// async global->LDS, 16B per lane: LDS dest = wave-uniform base + lane*16 (m97-verified).
__device__ __forceinline__ void gl_lds16(const void* g, void* l) {
  __builtin_amdgcn_global_load_lds(
      (const __attribute__((address_space(1))) uint32_t*)(uintptr_t)g,
      (__attribute__((address_space(3))) uint32_t*)(uintptr_t)l, 16, 0, 0);
}

// fast gelu (tanh approx): |err| <= ~1e-3, ~14 VALU ops (vs ~30 for erff)
__device__ __forceinline__ float gelu_f(float v) {
  const float y = 0.7978845608f * (v + 0.044715f * v * v * v);
  const float t = exp2f(y * 2.885390082f);  // e^{2y}
  const float th = 1.0f - 2.0f * __builtin_amdgcn_rcpf(t + 1.0f);
  return 0.5f * v * (1.0f + th);
}

#define MEG 1048576
#define PREP_CVT 12288        // 12M weight elems / 1024 per block

// ---------------- fused prep: weight cvt (f32->bf16) + RMSNorm pass1 ----------------
__global__ __launch_bounds__(256) void prep_k(const float* __restrict__ wq, const float* __restrict__ wk,
                                              const float* __restrict__ wv, const float* __restrict__ wo,
                                              const float* __restrict__ w1, const float* __restrict__ w2,
                                              u16* __restrict__ wqkv, u16* __restrict__ wob,
                                              u16* __restrict__ w1b, u16* __restrict__ w2b,
                                              const float* __restrict__ X, const float* __restrict__ G,
                                              u16* __restrict__ Hout) {
  __shared__ float red[4];
  const int bid = blockIdx.x;
  const int tid = threadIdx.x;
  if (bid < PREP_CVT) {  // weight convert
    const int n = (bid * 256 + tid) * 4;
    const float* src;
    u16* dst;
    int off;
    if (n < 3 * MEG) {
      dst = wqkv; off = n;
      src = (n < MEG) ? wq + n : (n < 2 * MEG ? wk + (n - MEG) : wv + (n - 2 * MEG));
    } else if (n < 4 * MEG) {
      dst = wob; off = n - 3 * MEG; src = wo + off;
    } else if (n < 8 * MEG) {
      dst = w1b; off = n - 4 * MEG; src = w1 + off;
    } else {
      dst = w2b; off = n - 8 * MEG; src = w2 + off;
    }
    const float4 v = *(const float4*)src;
    us4 o;
    o[0] = f2bf(v.x); o[1] = f2bf(v.y); o[2] = f2bf(v.z); o[3] = f2bf(v.w);
    *(us4*)&dst[off] = o;
  } else {  // RMSNorm pass 1
    const int row = bid - PREP_CVT;
    const float4 xx = *(const float4*)&X[(size_t)row * D_ + tid * 4];
    float v[4] = {xx.x, xx.y, xx.z, xx.w};
    float s = 0.f;
#pragma unroll
    for (int i = 0; i < 4; ++i) s += v[i] * v[i];
#pragma unroll
    for (int d = 1; d < 64; d <<= 1) s += __shfl_xor(s, d);
    if ((tid & 63) == 0) red[tid >> 6] = s;
    __syncthreads();
    s = red[0] + red[1] + red[2] + red[3];
    const float scale = rsqrtf(s * (1.0f / (float)D_) + 1e-5f);
    const float4 gg = *(const float4*)&G[tid * 4];
    us4 o;
    o[0] = f2bf(v[0] * scale * gg.x);
    o[1] = f2bf(v[1] * scale * gg.y);
    o[2] = f2bf(v[2] * scale * gg.z);
    o[3] = f2bf(v[3] * scale * gg.w);
    *(us4*)&Hout[(size_t)row * D_ + tid * 4] = o;
  }
}

// ---------------- fused WO-reduce + residual + RMSNorm: x2 = P0+P1+x; h2 = rmsnorm(x2)*g2 ----------------
__global__ __launch_bounds__(256) void rmsnorm_wo_k(const u16* __restrict__ P0, const u16* __restrict__ P1,
                                                    const float* __restrict__ X, const float* __restrict__ G,
                                                    float* __restrict__ X2, u16* __restrict__ Hout) {
  const int row = blockIdx.x;
  const int tid = threadIdx.x;
  const size_t off = (size_t)row * D_ + tid * 4;
  const us4 p0 = *(const us4*)&P0[off];
  const us4 p1 = *(const us4*)&P1[off];
  const float4 xx = *(const float4*)&X[off];
  float v[4];
  v[0] = bf2f(p0[0]) + bf2f(p1[0]) + xx.x;
  v[1] = bf2f(p0[1]) + bf2f(p1[1]) + xx.y;
  v[2] = bf2f(p0[2]) + bf2f(p1[2]) + xx.z;
  v[3] = bf2f(p0[3]) + bf2f(p1[3]) + xx.w;
  *(float4*)&X2[off] = float4{v[0], v[1], v[2], v[3]};
  float s = 0.f;
#pragma unroll
  for (int i = 0; i < 4; ++i) s += v[i] * v[i];
#pragma unroll
  for (int d = 1; d < 64; d <<= 1) s += __shfl_xor(s, d);
  __shared__ float red[4];
  if ((tid & 63) == 0) red[tid >> 6] = s;
  __syncthreads();
  s = red[0] + red[1] + red[2] + red[3];
  const float scale = rsqrtf(s * (1.0f / (float)D_) + 1e-5f);
  const float4 gg = *(const float4*)&G[tid * 4];
  us4 o;
  o[0] = f2bf(v[0] * scale * gg.x);
  o[1] = f2bf(v[1] * scale * gg.y);
  o[2] = f2bf(v[2] * scale * gg.z);
  o[3] = f2bf(v[3] * scale * gg.w);
  *(us4*)&Hout[off] = o;
}

// ---------------- FFN2 reduce: out = Q0 + Q1 + x2 (in place on d_out) ----------------
__global__ __launch_bounds__(256) void ffn2_red_k(const u16* __restrict__ Q0, const u16* __restrict__ Q1,
                                                  float* __restrict__ OUT) {
  const int i = (blockIdx.x * 256 + threadIdx.x) * 4;
  const us4 a = *(const us4*)&Q0[i];
  const us4 b = *(const us4*)&Q1[i];
  const float4 c = *(const float4*)&OUT[i];
  *(float4*)&OUT[i] = float4{bf2f(a[0]) + bf2f(b[0]) + c.x, bf2f(a[1]) + bf2f(b[1]) + c.y,
                             bf2f(a[2]) + bf2f(b[2]) + c.z, bf2f(a[3]) + bf2f(b[3]) + c.w};
}

// ---------------- 256x256-tile GEMM, 8 waves, counted-vmcnt 2-deep pipeline ----------------
// R13 verified the skeleton (raw s_barrier + vmcnt(8), never drain to 0) at 128^2; the
// 256^2 tile rides it: 64 MFMA per wave per barrier-pair (2x amortization), A/B refetch
// halves. Swizzle algebra carries over verbatim (lr = m + 256*kh; key (m>>1)&3 since
// 256*kh >> 1 == 0 mod 4). Exactly 8 gl_lds16/thread/tile -> same vmcnt counts.
// LDS 128 KiB (1 block/CU, 8 waves = 2/SIMD); launch_bounds(512,2) caps VGPR at 256
// (acc 128 + frags 48 + addr ~ 220, no spill).
// Wave grid 2M x 4N: per-wave output 128x64 (mt 0..7, nt 0..3).
// MODE 2: gelu store; MODE 4: QKV scatter (q pre-scaled by SCL; VT pair-permuted;
// 256-wide tiles never straddle Q/K/V since 1024 % 256 == 0).
template <int MODE>
__global__ __launch_bounds__(512, 2) void gemm_bt_k(const u16* __restrict__ A,
                                                    const u16* __restrict__ W,
                                                    u16* __restrict__ C0, u16* __restrict__ C1,
                                                    u16* __restrict__ C2, int N, int K) {
  __shared__ alignas(16) u16 As[2][512 * 32];
  __shared__ alignas(16) u16 Bs[2][512 * 32];
  const int tid = threadIdx.x;
  const int wv = tid >> 6, lane = tid & 63;
  const int r = lane & 15, quad = lane >> 4;
  const int nx = gridDim.x;
  const int nwg = nx * gridDim.y;  // 192 (QKV) / 256 (FFN1), %8 == 0
  const int orig = blockIdx.x + nx * blockIdx.y;
  const int id = (orig & 7) * (nwg >> 3) + (orig >> 3);
  const int bn = (id % nx) * 256;
  const int bm = (id / nx) * 256;
  const int row0 = (wv >> 2) * 128, col0 = (wv & 3) * 64;

  f32x4 acc[8][4] = {};

  // staging geometry: 2048 lane-slots of 16B per operand-tile (256 rows x 64 k);
  // chunk jj: c = (jj*8 + wv)*64 + lane (wave-contiguous for gl_lds16's linear dest).
  int sm[4], sh[4], sg[4];
#pragma unroll
  for (int jj = 0; jj < 4; ++jj) {
    const int c = (jj * 8 + wv) * 64 + lane;
    const int lr = c >> 2;
    sm[jj] = lr & 255;
    sh[jj] = lr >> 8;
    sg[jj] = (c & 3) ^ ((sm[jj] >> 1) & 3);
  }

  const int NT = K >> 6;
  // prologue: issue tiles 0 and 1 (8 loads each per thread)
#pragma unroll
  for (int jj = 0; jj < 4; ++jj) {
    const int l0 = ((jj * 8 + wv) * 64 + lane - lane) * 8 + 0;  // wave base; lane offset via HW
    (void)l0;
  }
#pragma unroll
  for (int jj = 0; jj < 4; ++jj) {
    const int c0 = ((jj * 8 + wv) * 64) * 8;
    gl_lds16(&A[(size_t)(bm + sm[jj]) * K + sh[jj] * 32 + sg[jj] * 8], &As[0][c0]);
    gl_lds16(&W[(size_t)(bn + sm[jj]) * K + sh[jj] * 32 + sg[jj] * 8], &Bs[0][c0]);
  }
  if (NT > 1) {
#pragma unroll
    for (int jj = 0; jj < 4; ++jj) {
      const int c0 = ((jj * 8 + wv) * 64) * 8;
      gl_lds16(&A[(size_t)(bm + sm[jj]) * K + 64 + sh[jj] * 32 + sg[jj] * 8], &As[1][c0]);
      gl_lds16(&W[(size_t)(bn + sm[jj]) * K + 64 + sh[jj] * 32 + sg[jj] * 8], &Bs[1][c0]);
    }
  }

  for (int t = 0; t < NT; ++t) {
    const int buf = t & 1;
    if (t + 1 < NT) asm volatile("s_waitcnt vmcnt(8)" ::: "memory");
    else            asm volatile("s_waitcnt vmcnt(0)" ::: "memory");
    __builtin_amdgcn_s_barrier();
    __builtin_amdgcn_s_setprio(1);
#pragma unroll
    for (int h = 0; h < 2; ++h) {
      short8 af[8], bf[4];
#pragma unroll
      for (int mt = 0; mt < 8; ++mt) {
        const int mr = row0 + mt * 16 + r;
        af[mt] = *(const short8*)&As[buf][(mr + 256 * h) * 32 + (quad ^ ((mr >> 1) & 3)) * 8];
      }
#pragma unroll
      for (int nt = 0; nt < 4; ++nt) {
        const int nr = col0 + nt * 16 + r;
        bf[nt] = *(const short8*)&Bs[buf][(nr + 256 * h) * 32 + (quad ^ ((nr >> 1) & 3)) * 8];
      }
#pragma unroll
      for (int mt = 0; mt < 8; ++mt)
#pragma unroll
        for (int nt = 0; nt < 4; ++nt)
          acc[mt][nt] = __builtin_amdgcn_mfma_f32_16x16x32_bf16(af[mt], bf[nt], acc[mt][nt], 0, 0, 0);
    }
    __builtin_amdgcn_s_setprio(0);
    __builtin_amdgcn_s_barrier();
    if (t + 2 < NT) {
      const int k2 = (t + 2) << 6;
#pragma unroll
      for (int jj = 0; jj < 4; ++jj) {
        const int c0 = ((jj * 8 + wv) * 64) * 8;
        gl_lds16(&A[(size_t)(bm + sm[jj]) * K + k2 + sh[jj] * 32 + sg[jj] * 8], &As[buf][c0]);
        gl_lds16(&W[(size_t)(bn + sm[jj]) * K + k2 + sh[jj] * 32 + sg[jj] * 8], &Bs[buf][c0]);
      }
    }
  }

  if constexpr (MODE == 2) {
#pragma unroll
    for (int mt = 0; mt < 8; ++mt)
#pragma unroll
      for (int nt = 0; nt < 4; ++nt)
#pragma unroll
        for (int i = 0; i < 4; ++i) {
          const int grow = bm + row0 + mt * 16 + quad * 4 + i;
          const int gcol = bn + col0 + nt * 16 + r;
          C0[(size_t)grow * N + gcol] = f2bf(gelu_f(acc[mt][nt][i]));
        }
  } else {  // MODE 4: QKV scatter. Tiles are pure Q/K (bn<2048) or pure V (bn>=2048).
    if (bn < 2048) {
#pragma unroll
      for (int mt = 0; mt < 8; ++mt) {
        const int grow0 = bm + row0 + mt * 16 + quad * 4;
#pragma unroll
        for (int nt = 0; nt < 4; ++nt) {
          const int gcol = bn + col0 + nt * 16 + r;
          u16* dst = (gcol < 1024) ? C0 : C1;
          const float sc = (gcol < 1024) ? SCL : 1.0f;  // pre-scale Q
          const int cc = gcol & 1023;
#pragma unroll
          for (int i = 0; i < 4; ++i)
            dst[(size_t)(grow0 + i) * 1024 + cc] = f2bf(acc[mt][nt][i] * sc);
        }
      }
    } else {
      // V: pair-permuted transpose (dword d of each 32-seq block = (V[d], V[d+16])).
#pragma unroll
      for (int mtp = 0; mtp < 8; mtp += 2) {
        const int tok0 = bm + row0 + mtp * 16 + quad * 4;
#pragma unroll
        for (int nt = 0; nt < 4; ++nt) {
          const int vcol = bn + col0 + nt * 16 + r - 2048;
          const size_t vtrow = (size_t)((tok0 >> 11) * 16 + (vcol >> 6)) * 64 + (vcol & 63);
#pragma unroll
          for (int i = 0; i < 4; ++i) {
            const int s = (tok0 + i) & 2047;
            const uint32_t pk =
                (uint32_t)f2bf(acc[mtp][nt][i]) | ((uint32_t)f2bf(acc[mtp + 1][nt][i]) << 16);
            *(uint32_t*)&C2[vtrow * 2048 + s + (s & 15)] = pk;
          }
        }
      }
    }
  }
}

// ---------------- split-K=2 GEMM, BK=64, counted-vmcnt 2-deep pipeline (128^2, R13-verified) ----------------
__global__ __launch_bounds__(256) void gemm_sk2_k(const u16* __restrict__ A,
                                                  const u16* __restrict__ W,
                                                  u16* __restrict__ P0, u16* __restrict__ P1,
                                                  int N, int K, int KS) {
  __shared__ alignas(16) u16 As[2][256 * 32];
  __shared__ alignas(16) u16 Bs[2][256 * 32];
  const int tid = threadIdx.x;
  const int wv = tid >> 6, lane = tid & 63;
  const int r = lane & 15, quad = lane >> 4;
  const int orig = blockIdx.x + 8 * (blockIdx.y + 32 * blockIdx.z);
  const int id = (orig & 7) * 64 + (orig >> 3);
  const int bn = (id & 7) * 128;
  const int bm = ((id >> 3) & 31) * 128;
  const int bz = id >> 8;
  const int row0 = (wv >> 1) * 64, col0 = (wv & 1) * 64;
  const int koff = bz * KS;
  u16* P = bz ? P1 : P0;

  f32x4 acc[4][4] = {};

  int sm[4], sh[4], sg[4];
#pragma unroll
  for (int jj = 0; jj < 4; ++jj) {
    const int c = wv * 256 + jj * 64 + lane;
    const int lr = c >> 2;
    sm[jj] = lr & 127;
    sh[jj] = lr >> 7;
    sg[jj] = (c & 3) ^ ((sm[jj] >> 1) & 3);
  }

  const int NT = KS >> 6;
#pragma unroll
  for (int jj = 0; jj < 4; ++jj) {
    const int l0 = (wv * 256 + jj * 64) * 8;
    gl_lds16(&A[(size_t)(bm + sm[jj]) * K + koff + sh[jj] * 32 + sg[jj] * 8], &As[0][l0]);
    gl_lds16(&W[(size_t)(bn + sm[jj]) * K + koff + sh[jj] * 32 + sg[jj] * 8], &Bs[0][l0]);
  }
  if (NT > 1) {
#pragma unroll
    for (int jj = 0; jj < 4; ++jj) {
      const int l0 = (wv * 256 + jj * 64) * 8;
      gl_lds16(&A[(size_t)(bm + sm[jj]) * K + koff + 64 + sh[jj] * 32 + sg[jj] * 8], &As[1][l0]);
      gl_lds16(&W[(size_t)(bn + sm[jj]) * K + koff + 64 + sh[jj] * 32 + sg[jj] * 8], &Bs[1][l0]);
    }
  }

  for (int t = 0; t < NT; ++t) {
    const int buf = t & 1;
    if (t + 1 < NT) asm volatile("s_waitcnt vmcnt(8)" ::: "memory");
    else            asm volatile("s_waitcnt vmcnt(0)" ::: "memory");
    __builtin_amdgcn_s_barrier();
    __builtin_amdgcn_s_setprio(1);
#pragma unroll
    for (int h = 0; h < 2; ++h) {
      short8 af[4], bf[4];
#pragma unroll
      for (int mt = 0; mt < 4; ++mt) {
        const int mr = row0 + mt * 16 + r;
        af[mt] = *(const short8*)&As[buf][(mr + 128 * h) * 32 + (quad ^ ((mr >> 1) & 3)) * 8];
      }
#pragma unroll
      for (int nt = 0; nt < 4; ++nt) {
        const int nr = col0 + nt * 16 + r;
        bf[nt] = *(const short8*)&Bs[buf][(nr + 128 * h) * 32 + (quad ^ ((nr >> 1) & 3)) * 8];
      }
#pragma unroll
      for (int mt = 0; mt < 4; ++mt)
#pragma unroll
        for (int nt = 0; nt < 4; ++nt)
          acc[mt][nt] = __builtin_amdgcn_mfma_f32_16x16x32_bf16(af[mt], bf[nt], acc[mt][nt], 0, 0, 0);
    }
    __builtin_amdgcn_s_setprio(0);
    __builtin_amdgcn_s_barrier();
    if (t + 2 < NT) {
      const int k2 = koff + ((t + 2) << 6);
#pragma unroll
      for (int jj = 0; jj < 4; ++jj) {
        const int l0 = (wv * 256 + jj * 64) * 8;
        gl_lds16(&A[(size_t)(bm + sm[jj]) * K + k2 + sh[jj] * 32 + sg[jj] * 8], &As[buf][l0]);
        gl_lds16(&W[(size_t)(bn + sm[jj]) * K + k2 + sh[jj] * 32 + sg[jj] * 8], &Bs[buf][l0]);
      }
    }
  }

#pragma unroll
  for (int mt = 0; mt < 4; ++mt)
#pragma unroll
    for (int nt = 0; nt < 4; ++nt)
#pragma unroll
      for (int i = 0; i < 4; ++i) {
        const int grow = bm + row0 + mt * 16 + quad * 4 + i;
        const int gcol = bn + col0 + nt * 16 + r;
        P[(size_t)grow * N + gcol] = f2bf(acc[mt][nt][i]);
      }
}

// ---------------- Flash attention v13 (unchanged from R12: own-your-rows + LPT pairing) ----------------
#define ATTN_BODY(BUF, J0, RINK, RINV, ROUTK, ROUTV, DO_PF, DO_WR)                                 \
  {                                                                                                \
    __syncthreads();                                                                               \
    if (DO_PF) {                                                                                   \
      ROUTK = *(const short8*)&Kb[(size_t)((J0) + 64 + krow) * D_ + kg * 8];                       \
      ROUTV = *(const short8*)&VTb[(size_t)vrow * 2048 + (J0) + 64 + vg * 8];                      \
    }                                                                                              \
    f32x4 z[2][2];                                                                                 \
    __builtin_amdgcn_s_setprio(1);                                                                 \
    _Pragma("unroll") for (int kt = 0; kt < 2; ++kt) {                                             \
      const short8 kf0 = *(const short8*)&Ks[BUF][(kt * 16 + r) * 72 + quad * 8];                  \
      const short8 kf1 = *(const short8*)&Ks[BUF][(kt * 16 + r) * 72 + 32 + quad * 8];             \
      _Pragma("unroll") for (int f = 0; f < 2; ++f) {                                              \
        f32x4 zz = {};                                                                             \
        zz = __builtin_amdgcn_mfma_f32_16x16x32_bf16(qf[f][0], kf0, zz, 0, 0, 0);                  \
        zz = __builtin_amdgcn_mfma_f32_16x16x32_bf16(qf[f][1], kf1, zz, 0, 0, 0);                  \
        z[f][kt] = zz;                                                                             \
      }                                                                                            \
    }                                                                                              \
    __builtin_amdgcn_s_setprio(0);                                                                 \
    const bool masked = ((J0) + 31 > m0);                                                          \
    _Pragma("unroll") for (int f = 0; f < 2; ++f) _Pragma("unroll") for (int i = 0; i < 4; ++i) {  \
      const int qrow = m0 + f * 16 + quad * 4 + i;                                                 \
      float v0 = z[f][0][i];                                                                       \
      float v1 = z[f][1][i];                                                                       \
      if (masked) {                                                                                \
        if ((J0) + r > qrow) v0 = -128.f;                                                          \
        if ((J0) + 16 + r > qrow) v1 = -128.f;                                                     \
      }                                                                                            \
      *(uint32_t*)&Psw[(f * 16 + quad * 4 + i) * 40 + r * 2] = pack2bf(exp2f(v0), exp2f(v1));      \
    }                                                                                              \
    asm volatile("s_waitcnt lgkmcnt(0)" ::: "memory");                                             \
    short8 vf[4];                                                                                  \
    _Pragma("unroll") for (int nt = 0; nt < 4; ++nt)                                               \
        vf[nt] = *(const short8*)&Vs[BUF][(nt * 16 + r) * 40 + quad * 8];                          \
    __builtin_amdgcn_s_setprio(1);                                                                 \
    _Pragma("unroll") for (int f = 0; f < 2; ++f) {                                                \
      const short8 pf = *(const short8*)&Psw[(f * 16 + r) * 40 + quad * 8];                        \
      _Pragma("unroll") for (int nt = 0; nt < 4; ++nt)                                             \
          oacc[f][nt] = __builtin_amdgcn_mfma_f32_16x16x32_bf16(pf, vf[nt], oacc[f][nt], 0, 0, 0); \
      lacc[f] = __builtin_amdgcn_mfma_f32_16x16x32_bf16(pf, onesv, lacc[f], 0, 0, 0);              \
    }                                                                                              \
    __builtin_amdgcn_s_setprio(0);                                                                 \
    if (DO_WR) {                                                                                   \
      *(short8*)&Ks[(BUF) ^ 1][krow * 72 + kg * 8] = RINK;                                         \
      *(short8*)&Vs[(BUF) ^ 1][vrow * 40 + vg * 8] = RINV;                                         \
    }                                                                                              \
  }

__global__ __launch_bounds__(256, 2) void attn_k(const u16* __restrict__ Q,
                                                 const u16* __restrict__ Kx,
                                                 const u16* __restrict__ VT,
                                                 u16* __restrict__ O) {
  __shared__ alignas(16) u16 Ks[2][32 * 72];
  __shared__ alignas(16) u16 Vs[2][64 * 40];
  __shared__ alignas(16) u16 Ps[4][32 * 40];

  const int tid = threadIdx.x;
  const int wv = tid >> 6, lane = tid & 63;
  const int r = lane & 15, quad = lane >> 4;

  // LPT + same-CU pairing: i in [0,512). wave w: 0 = long (bx 15..8), 1 = short (bx 0..7).
  // Blocks i and i+256 share a CU (%8 XCD round-robin) and get complementary bx.
  const int i_ = blockIdx.x + 16 * blockIdx.y;
  const int w = i_ >> 8;
  const int j = i_ & 255;
  const int xcd = j & 7;
  const int u = j >> 3;                 // 0..31
  const int bh = xcd * 4 + (u >> 3);    // 4 bh per XCD (2MB KV in L2)
  const int s = u & 7;
  const int bx = w ? s : (15 - s);
  const int b = bh >> 4, hh = bh & 15;

  const int niter = (bx + 1) * 4;  // multiple of 4
  const int m0 = bx * 128 + wv * 32;
  const size_t base = (size_t)b * S_ * D_ + (size_t)hh * DH_;
  const u16* Qb = Q + base;
  const u16* Kb = Kx + base;
  const u16* VTb = VT + (size_t)bh * 64 * 2048;
  u16* Psw = &Ps[wv][0];

  short8 qf[2][2];
#pragma unroll
  for (int f = 0; f < 2; ++f) {
    qf[f][0] = *(const short8*)&Qb[(size_t)(m0 + f * 16 + r) * D_ + quad * 8];
    qf[f][1] = *(const short8*)&Qb[(size_t)(m0 + f * 16 + r) * D_ + 32 + quad * 8];
  }

  short8 onesv;
#pragma unroll
  for (int e = 0; e < 8; ++e) onesv[e] = (short)0x3F80;

  f32x4 oacc[2][4] = {};
  f32x4 lacc[2] = {};

  const int krow = tid >> 3, kg = tid & 7;
  const int vrow = tid >> 2, vg = tid & 3;

  // prologue: stage iter 0 into buf0; issue iter-1 loads into regA
  *(short8*)&Ks[0][krow * 72 + kg * 8] = *(const short8*)&Kb[(size_t)krow * D_ + kg * 8];
  *(short8*)&Vs[0][vrow * 40 + vg * 8] = *(const short8*)&VTb[(size_t)vrow * 2048 + vg * 8];
  short8 kA, vA, kB, vB;
  kA = *(const short8*)&Kb[(size_t)(32 + krow) * D_ + kg * 8];
  vA = *(const short8*)&VTb[(size_t)vrow * 2048 + 32 + vg * 8];

  for (int it = 0; it < niter; it += 2) {
    const int j0 = it * 32;
    ATTN_BODY(0, j0, kA, vA, kB, vB, (it + 2 < niter), true);
    ATTN_BODY(1, j0 + 32, kB, vB, kA, vA, (it + 3 < niter), (it + 2 < niter));
  }

  // epilogue: O = oacc / l, written directly (lacc holds the row sum in every lane).
#pragma unroll
  for (int f = 0; f < 2; ++f) {
#pragma unroll
    for (int i = 0; i < 4; ++i) {
      const int qrow = m0 + f * 16 + quad * 4 + i;
      const float linv = 1.0f / lacc[f][i];
#pragma unroll
      for (int nt = 0; nt < 4; ++nt)
        O[base + (size_t)qrow * D_ + nt * 16 + r] = f2bf(oacc[f][nt][i] * linv);
    }
  }
}

extern "C" void kernel_launch(void* const* d_in, const int* in_sizes, int n_in,
                              void* d_out, int out_size, void* d_ws, size_t ws_size,
                              hipStream_t stream) {
  (void)in_sizes; (void)n_in; (void)out_size; (void)ws_size;
  const float* x   = (const float*)d_in[0];
  const float* wq  = (const float*)d_in[1];
  const float* wk  = (const float*)d_in[2];
  const float* wvp = (const float*)d_in[3];
  const float* wo  = (const float*)d_in[4];
  const float* w1  = (const float*)d_in[5];
  const float* w2  = (const float*)d_in[6];
  const float* g1  = (const float*)d_in[7];
  const float* g2  = (const float*)d_in[8];
  float* out = (float*)d_out;  // x2 -> final output

  u16* ws = (u16*)d_ws;
  const size_t TD = (size_t)M_TOK * D_;  // 4M elems (8 MB)
  u16* h    = ws;            // slot0: h -> o -> t[0]
  u16* q    = ws + 1 * TD;   // slot1: q -> P0 -> t[1]
  u16* k    = ws + 2 * TD;   // slot2: k -> P1 -> t[2]
  u16* vt   = ws + 3 * TD;   // slot3: vt -> t[3]
  u16* h2   = ws + 4 * TD;   // slot4: h2 -> Q0
  u16* o    = h;             // attn writes o directly (h dead after QKV gemm)
  u16* t    = ws;            // FFN1 out spans slots 0..3
  u16* P0   = q;             // WO partials (q,k dead)
  u16* P1   = k;
  u16* Q0   = h2;            // FFN2 partials (h2 dead after FFN1)
  u16* wqkv = ws + 5 * TD;
  u16* wob  = wqkv + 3 * MEG;
  u16* w1b  = wob + 1 * MEG;
  u16* w2b  = w1b + 4 * MEG;
  u16* Q1   = w2b + 4 * MEG;  // tail: +8 MB (total ws ~73 MB)

  const dim3 blk(256);
  const dim3 blk512(512);

  prep_k<<<PREP_CVT + M_TOK, blk, 0, stream>>>(wq, wk, wvp, wo, w1, w2, wqkv, wob, w1b, w2b,
                                               x, g1, h);
  gemm_bt_k<4><<<dim3(12, 16), blk512, 0, stream>>>(h, wqkv, q, k, vt, 3072, 1024);
  attn_k<<<dim3(16, 32), blk, 0, stream>>>(q, k, vt, o);
  gemm_sk2_k<<<dim3(8, 32, 2), blk, 0, stream>>>(o, wob, P0, P1, 1024, 1024, 512);    // WO partials
  rmsnorm_wo_k<<<M_TOK, blk, 0, stream>>>(P0, P1, x, g2, out, h2);                    // x2 + h2 fused
  gemm_bt_k<2><<<dim3(16, 16), blk512, 0, stream>>>(h2, w1b, t, nullptr, nullptr, 4096, 1024);
  gemm_sk2_k<<<dim3(8, 32, 2), blk, 0, stream>>>(t, w2b, Q0, Q1, 1024, 4096, 2048);   // FFN2 partials
  ffn2_red_k<<<4096, blk, 0, stream>>>(Q0, Q1, out);                                  // out = Q0+Q1+x2
}

// Round 15
// 312.109 us; speedup vs baseline: 1.0151x; 1.0151x over previous
//
#include <hip/hip_runtime.h>
#include <cstdint>

#define B_ 2
#define S_ 2048
#define D_ 1024
#define H_ 16
#define DH_ 64
#define FF_ 4096
#define M_TOK (B_ * S_)  // 4096 token rows

typedef __attribute__((ext_vector_type(8))) short short8;
typedef __attribute__((ext_vector_type(4))) float f32x4;
typedef __attribute__((ext_vector_type(4))) unsigned short us4;

typedef unsigned short u16;

#define SCL 0.18033688011112042f /* 0.125 * log2(e), folded into Q at QKV epilogue */

__device__ __forceinline__ float bf2f(u16 u) {
  union { uint32_t u; float f; } x;
  x.u = ((uint32_t)u) << 16;
  return x.f;
}
__device__ __forceinline__ u16 f2bf(float f) {
  union { float f; uint32_t u; } x;
  x.f = f;
  uint32_t r = x.u + 0x7FFFu + ((x.u >> 16) & 1u);  // RNE
  return (u16)(r >> 16);
}

// pack two f32 -> u32 of two bf16 (lo=a, hi=b); round-half-up (values positive here).
__device__ __forceinline__ uint32_t pack2bf(float a, float b) {
  union { float f; uint32_t u; } x, y;
  x.f = a; y.f = b;
#if __has_builtin(__builtin_amdgcn_perm)
  // v_perm_b32: S0=hi-src, S1=lo-src; sel bytes {7,6,3,2} = {b.b3,b.b2,a.b3,a.b2}
  return __builtin_amdgcn_perm(y.u + 0x8000u, x.u + 0x8000u, 0x07060302u);
#else
  return ((x.u + 0x8000u) >> 16) | ((y.u + 0x8000u) & 0xFFFF0000u);
#endif
}

// async global->LDS, 16B per lane: LDS dest = wave-uniform base + lane*16 (m97-verified).
__device__ __forceinline__ void gl_lds16(const void* g, void* l) {
  __builtin_amdgcn_global_load_lds(
      (const __attribute__((address_space(1))) uint32_t*)(uintptr_t)g,
      (__attribute__((address_space(3))) uint32_t*)(uintptr_t)l, 16, 0, 0);
}

// fast gelu (tanh approx): |err| <= ~1e-3, ~14 VALU ops (vs ~30 for erff)
__device__ __forceinline__ float gelu_f(float v) {
  const float y = 0.7978845608f * (v + 0.044715f * v * v * v);
  const float t = exp2f(y * 2.885390082f);  // e^{2y}
  const float th = 1.0f - 2.0f * __builtin_amdgcn_rcpf(t + 1.0f);
  return 0.5f * v * (1.0f + th);
}

#define MEG 1048576
#define PREP_CVT 12288        // 12M weight elems / 1024 per block

// ---------------- fused prep: weight cvt (f32->bf16) + RMSNorm pass1 ----------------
__global__ __launch_bounds__(256) void prep_k(const float* __restrict__ wq, const float* __restrict__ wk,
                                              const float* __restrict__ wv, const float* __restrict__ wo,
                                              const float* __restrict__ w1, const float* __restrict__ w2,
                                              u16* __restrict__ wqkv, u16* __restrict__ wob,
                                              u16* __restrict__ w1b, u16* __restrict__ w2b,
                                              const float* __restrict__ X, const float* __restrict__ G,
                                              u16* __restrict__ Hout) {
  __shared__ float red[4];
  const int bid = blockIdx.x;
  const int tid = threadIdx.x;
  if (bid < PREP_CVT) {  // weight convert
    const int n = (bid * 256 + tid) * 4;
    const float* src;
    u16* dst;
    int off;
    if (n < 3 * MEG) {
      dst = wqkv; off = n;
      src = (n < MEG) ? wq + n : (n < 2 * MEG ? wk + (n - MEG) : wv + (n - 2 * MEG));
    } else if (n < 4 * MEG) {
      dst = wob; off = n - 3 * MEG; src = wo + off;
    } else if (n < 8 * MEG) {
      dst = w1b; off = n - 4 * MEG; src = w1 + off;
    } else {
      dst = w2b; off = n - 8 * MEG; src = w2 + off;
    }
    const float4 v = *(const float4*)src;
    us4 o;
    o[0] = f2bf(v.x); o[1] = f2bf(v.y); o[2] = f2bf(v.z); o[3] = f2bf(v.w);
    *(us4*)&dst[off] = o;
  } else {  // RMSNorm pass 1
    const int row = bid - PREP_CVT;
    const float4 xx = *(const float4*)&X[(size_t)row * D_ + tid * 4];
    float v[4] = {xx.x, xx.y, xx.z, xx.w};
    float s = 0.f;
#pragma unroll
    for (int i = 0; i < 4; ++i) s += v[i] * v[i];
#pragma unroll
    for (int d = 1; d < 64; d <<= 1) s += __shfl_xor(s, d);
    if ((tid & 63) == 0) red[tid >> 6] = s;
    __syncthreads();
    s = red[0] + red[1] + red[2] + red[3];
    const float scale = rsqrtf(s * (1.0f / (float)D_) + 1e-5f);
    const float4 gg = *(const float4*)&G[tid * 4];
    us4 o;
    o[0] = f2bf(v[0] * scale * gg.x);
    o[1] = f2bf(v[1] * scale * gg.y);
    o[2] = f2bf(v[2] * scale * gg.z);
    o[3] = f2bf(v[3] * scale * gg.w);
    *(us4*)&Hout[(size_t)row * D_ + tid * 4] = o;
  }
}

// ---------------- fused WO-reduce + residual + RMSNorm: x2 = P0+P1+x; h2 = rmsnorm(x2)*g2 ----------------
__global__ __launch_bounds__(256) void rmsnorm_wo_k(const u16* __restrict__ P0, const u16* __restrict__ P1,
                                                    const float* __restrict__ X, const float* __restrict__ G,
                                                    float* __restrict__ X2, u16* __restrict__ Hout) {
  const int row = blockIdx.x;
  const int tid = threadIdx.x;
  const size_t off = (size_t)row * D_ + tid * 4;
  const us4 p0 = *(const us4*)&P0[off];
  const us4 p1 = *(const us4*)&P1[off];
  const float4 xx = *(const float4*)&X[off];
  float v[4];
  v[0] = bf2f(p0[0]) + bf2f(p1[0]) + xx.x;
  v[1] = bf2f(p0[1]) + bf2f(p1[1]) + xx.y;
  v[2] = bf2f(p0[2]) + bf2f(p1[2]) + xx.z;
  v[3] = bf2f(p0[3]) + bf2f(p1[3]) + xx.w;
  *(float4*)&X2[off] = float4{v[0], v[1], v[2], v[3]};
  float s = 0.f;
#pragma unroll
  for (int i = 0; i < 4; ++i) s += v[i] * v[i];
#pragma unroll
  for (int d = 1; d < 64; d <<= 1) s += __shfl_xor(s, d);
  __shared__ float red[4];
  if ((tid & 63) == 0) red[tid >> 6] = s;
  __syncthreads();
  s = red[0] + red[1] + red[2] + red[3];
  const float scale = rsqrtf(s * (1.0f / (float)D_) + 1e-5f);
  const float4 gg = *(const float4*)&G[tid * 4];
  us4 o;
  o[0] = f2bf(v[0] * scale * gg.x);
  o[1] = f2bf(v[1] * scale * gg.y);
  o[2] = f2bf(v[2] * scale * gg.z);
  o[3] = f2bf(v[3] * scale * gg.w);
  *(us4*)&Hout[off] = o;
}

// ---------------- FFN2 reduce: out = Q0 + Q1 + x2 (in place on d_out) ----------------
__global__ __launch_bounds__(256) void ffn2_red_k(const u16* __restrict__ Q0, const u16* __restrict__ Q1,
                                                  float* __restrict__ OUT) {
  const int i = (blockIdx.x * 256 + threadIdx.x) * 4;
  const us4 a = *(const us4*)&Q0[i];
  const us4 b = *(const us4*)&Q1[i];
  const float4 c = *(const float4*)&OUT[i];
  *(float4*)&OUT[i] = float4{bf2f(a[0]) + bf2f(b[0]) + c.x, bf2f(a[1]) + bf2f(b[1]) + c.y,
                             bf2f(a[2]) + bf2f(b[2]) + c.z, bf2f(a[3]) + bf2f(b[3]) + c.w};
}

// ---------------- BK=64 GEMM, counted-vmcnt 2-deep pipeline (R13-verified, 315.7us config) ----------------
// RAW s_barrier + manual s_waitcnt vmcnt(8): next tile's 8 global_load_lds stay IN FLIGHT
// across barriers (never drain to 0), hiding the L2/HBM latency that capped MfmaUtil under
// __syncthreads' vmcnt(0) drain. R14's 256^2 attempt REFUTED: coarse 64-MFMA cluster at
// 2 waves/SIMD is latency-bound (MfmaUtil 15.6%) -- 256^2 needs the full 8-phase fine
// interleave (m196/m201), a race-prone rewrite. 128^2 + this skeleton is the sweet spot.
// MODE 2: gelu store; MODE 4: QKV scatter (q pre-scaled by SCL; VT pair-permuted).
template <int MODE>
__global__ __launch_bounds__(256) void gemm_bt_k(const u16* __restrict__ A,
                                                 const u16* __restrict__ W,
                                                 u16* __restrict__ C0, u16* __restrict__ C1,
                                                 u16* __restrict__ C2, int N, int K) {
  __shared__ alignas(16) u16 As[2][256 * 32];
  __shared__ alignas(16) u16 Bs[2][256 * 32];
  const int tid = threadIdx.x;
  const int wv = tid >> 6, lane = tid & 63;
  const int r = lane & 15, quad = lane >> 4;
  const int nx = gridDim.x;
  const int nwg = nx * gridDim.y;  // always %8 == 0 here
  const int orig = blockIdx.x + nx * blockIdx.y;
  const int id = (orig & 7) * (nwg >> 3) + (orig >> 3);
  const int bn = (id % nx) * 128;
  const int bm = (id / nx) * 128;
  const int row0 = (wv >> 1) * 64, col0 = (wv & 1) * 64;

  f32x4 acc[4][4] = {};

  int sm[4], sh[4], sg[4];
#pragma unroll
  for (int jj = 0; jj < 4; ++jj) {
    const int c = wv * 256 + jj * 64 + lane;
    const int lr = c >> 2;
    sm[jj] = lr & 127;
    sh[jj] = lr >> 7;
    sg[jj] = (c & 3) ^ ((sm[jj] >> 1) & 3);
  }

  const int NT = K >> 6;
  // prologue: issue tiles 0 and 1 (8 loads each)
#pragma unroll
  for (int jj = 0; jj < 4; ++jj) {
    const int l0 = (wv * 256 + jj * 64) * 8;
    gl_lds16(&A[(size_t)(bm + sm[jj]) * K + sh[jj] * 32 + sg[jj] * 8], &As[0][l0]);
    gl_lds16(&W[(size_t)(bn + sm[jj]) * K + sh[jj] * 32 + sg[jj] * 8], &Bs[0][l0]);
  }
  if (NT > 1) {
#pragma unroll
    for (int jj = 0; jj < 4; ++jj) {
      const int l0 = (wv * 256 + jj * 64) * 8;
      gl_lds16(&A[(size_t)(bm + sm[jj]) * K + 64 + sh[jj] * 32 + sg[jj] * 8], &As[1][l0]);
      gl_lds16(&W[(size_t)(bn + sm[jj]) * K + 64 + sh[jj] * 32 + sg[jj] * 8], &Bs[1][l0]);
    }
  }

  for (int t = 0; t < NT; ++t) {
    const int buf = t & 1;
    if (t + 1 < NT) asm volatile("s_waitcnt vmcnt(8)" ::: "memory");
    else            asm volatile("s_waitcnt vmcnt(0)" ::: "memory");
    __builtin_amdgcn_s_barrier();
    __builtin_amdgcn_s_setprio(1);
#pragma unroll
    for (int h = 0; h < 2; ++h) {
      short8 af[4], bf[4];
#pragma unroll
      for (int mt = 0; mt < 4; ++mt) {
        const int mr = row0 + mt * 16 + r;
        af[mt] = *(const short8*)&As[buf][(mr + 128 * h) * 32 + (quad ^ ((mr >> 1) & 3)) * 8];
      }
#pragma unroll
      for (int nt = 0; nt < 4; ++nt) {
        const int nr = col0 + nt * 16 + r;
        bf[nt] = *(const short8*)&Bs[buf][(nr + 128 * h) * 32 + (quad ^ ((nr >> 1) & 3)) * 8];
      }
#pragma unroll
      for (int mt = 0; mt < 4; ++mt)
#pragma unroll
        for (int nt = 0; nt < 4; ++nt)
          acc[mt][nt] = __builtin_amdgcn_mfma_f32_16x16x32_bf16(af[mt], bf[nt], acc[mt][nt], 0, 0, 0);
    }
    __builtin_amdgcn_s_setprio(0);
    __builtin_amdgcn_s_barrier();
    if (t + 2 < NT) {
      const int k2 = (t + 2) << 6;
#pragma unroll
      for (int jj = 0; jj < 4; ++jj) {
        const int l0 = (wv * 256 + jj * 64) * 8;
        gl_lds16(&A[(size_t)(bm + sm[jj]) * K + k2 + sh[jj] * 32 + sg[jj] * 8], &As[buf][l0]);
        gl_lds16(&W[(size_t)(bn + sm[jj]) * K + k2 + sh[jj] * 32 + sg[jj] * 8], &Bs[buf][l0]);
      }
    }
  }

  if constexpr (MODE == 2) {
#pragma unroll
    for (int mt = 0; mt < 4; ++mt)
#pragma unroll
      for (int nt = 0; nt < 4; ++nt)
#pragma unroll
        for (int i = 0; i < 4; ++i) {
          const int grow = bm + row0 + mt * 16 + quad * 4 + i;
          const int gcol = bn + col0 + nt * 16 + r;
          C0[(size_t)grow * N + gcol] = f2bf(gelu_f(acc[mt][nt][i]));
        }
  } else {  // MODE 4: QKV scatter. Blocks are pure Q/K (bn<2048) or pure V (bn>=2048).
    if (bn < 2048) {
#pragma unroll
      for (int mt = 0; mt < 4; ++mt) {
        const int grow0 = bm + row0 + mt * 16 + quad * 4;
#pragma unroll
        for (int nt = 0; nt < 4; ++nt) {
          const int gcol = bn + col0 + nt * 16 + r;
          u16* dst = (gcol < 1024) ? C0 : C1;
          const float sc = (gcol < 1024) ? SCL : 1.0f;  // pre-scale Q
          const int cc = gcol & 1023;
#pragma unroll
          for (int i = 0; i < 4; ++i)
            dst[(size_t)(grow0 + i) * 1024 + cc] = f2bf(acc[mt][nt][i] * sc);
        }
      }
    } else {
      // V: pair-permuted transpose (dword d of each 32-seq block = (V[d], V[d+16])).
#pragma unroll
      for (int mtp = 0; mtp < 4; mtp += 2) {
        const int tok0 = bm + row0 + mtp * 16 + quad * 4;
#pragma unroll
        for (int nt = 0; nt < 4; ++nt) {
          const int vcol = bn + col0 + nt * 16 + r - 2048;
          const size_t vtrow = (size_t)((tok0 >> 11) * 16 + (vcol >> 6)) * 64 + (vcol & 63);
#pragma unroll
          for (int i = 0; i < 4; ++i) {
            const int s = (tok0 + i) & 2047;
            const uint32_t pk =
                (uint32_t)f2bf(acc[mtp][nt][i]) | ((uint32_t)f2bf(acc[mtp + 1][nt][i]) << 16);
            *(uint32_t*)&C2[vtrow * 2048 + s + (s & 15)] = pk;
          }
        }
      }
    }
  }
}

// ---------------- split-K=2 GEMM, BK=64, counted-vmcnt 2-deep pipeline (same skeleton) ----------------
__global__ __launch_bounds__(256) void gemm_sk2_k(const u16* __restrict__ A,
                                                  const u16* __restrict__ W,
                                                  u16* __restrict__ P0, u16* __restrict__ P1,
                                                  int N, int K, int KS) {
  __shared__ alignas(16) u16 As[2][256 * 32];
  __shared__ alignas(16) u16 Bs[2][256 * 32];
  const int tid = threadIdx.x;
  const int wv = tid >> 6, lane = tid & 63;
  const int r = lane & 15, quad = lane >> 4;
  const int orig = blockIdx.x + 8 * (blockIdx.y + 32 * blockIdx.z);
  const int id = (orig & 7) * 64 + (orig >> 3);
  const int bn = (id & 7) * 128;
  const int bm = ((id >> 3) & 31) * 128;
  const int bz = id >> 8;
  const int row0 = (wv >> 1) * 64, col0 = (wv & 1) * 64;
  const int koff = bz * KS;
  u16* P = bz ? P1 : P0;

  f32x4 acc[4][4] = {};

  int sm[4], sh[4], sg[4];
#pragma unroll
  for (int jj = 0; jj < 4; ++jj) {
    const int c = wv * 256 + jj * 64 + lane;
    const int lr = c >> 2;
    sm[jj] = lr & 127;
    sh[jj] = lr >> 7;
    sg[jj] = (c & 3) ^ ((sm[jj] >> 1) & 3);
  }

  const int NT = KS >> 6;
#pragma unroll
  for (int jj = 0; jj < 4; ++jj) {
    const int l0 = (wv * 256 + jj * 64) * 8;
    gl_lds16(&A[(size_t)(bm + sm[jj]) * K + koff + sh[jj] * 32 + sg[jj] * 8], &As[0][l0]);
    gl_lds16(&W[(size_t)(bn + sm[jj]) * K + koff + sh[jj] * 32 + sg[jj] * 8], &Bs[0][l0]);
  }
  if (NT > 1) {
#pragma unroll
    for (int jj = 0; jj < 4; ++jj) {
      const int l0 = (wv * 256 + jj * 64) * 8;
      gl_lds16(&A[(size_t)(bm + sm[jj]) * K + koff + 64 + sh[jj] * 32 + sg[jj] * 8], &As[1][l0]);
      gl_lds16(&W[(size_t)(bn + sm[jj]) * K + koff + 64 + sh[jj] * 32 + sg[jj] * 8], &Bs[1][l0]);
    }
  }

  for (int t = 0; t < NT; ++t) {
    const int buf = t & 1;
    if (t + 1 < NT) asm volatile("s_waitcnt vmcnt(8)" ::: "memory");
    else            asm volatile("s_waitcnt vmcnt(0)" ::: "memory");
    __builtin_amdgcn_s_barrier();
    __builtin_amdgcn_s_setprio(1);
#pragma unroll
    for (int h = 0; h < 2; ++h) {
      short8 af[4], bf[4];
#pragma unroll
      for (int mt = 0; mt < 4; ++mt) {
        const int mr = row0 + mt * 16 + r;
        af[mt] = *(const short8*)&As[buf][(mr + 128 * h) * 32 + (quad ^ ((mr >> 1) & 3)) * 8];
      }
#pragma unroll
      for (int nt = 0; nt < 4; ++nt) {
        const int nr = col0 + nt * 16 + r;
        bf[nt] = *(const short8*)&Bs[buf][(nr + 128 * h) * 32 + (quad ^ ((nr >> 1) & 3)) * 8];
      }
#pragma unroll
      for (int mt = 0; mt < 4; ++mt)
#pragma unroll
        for (int nt = 0; nt < 4; ++nt)
          acc[mt][nt] = __builtin_amdgcn_mfma_f32_16x16x32_bf16(af[mt], bf[nt], acc[mt][nt], 0, 0, 0);
    }
    __builtin_amdgcn_s_setprio(0);
    __builtin_amdgcn_s_barrier();
    if (t + 2 < NT) {
      const int k2 = koff + ((t + 2) << 6);
#pragma unroll
      for (int jj = 0; jj < 4; ++jj) {
        const int l0 = (wv * 256 + jj * 64) * 8;
        gl_lds16(&A[(size_t)(bm + sm[jj]) * K + k2 + sh[jj] * 32 + sg[jj] * 8], &As[buf][l0]);
        gl_lds16(&W[(size_t)(bn + sm[jj]) * K + k2 + sh[jj] * 32 + sg[jj] * 8], &Bs[buf][l0]);
      }
    }
  }

#pragma unroll
  for (int mt = 0; mt < 4; ++mt)
#pragma unroll
    for (int nt = 0; nt < 4; ++nt)
#pragma unroll
      for (int i = 0; i < 4; ++i) {
        const int grow = bm + row0 + mt * 16 + quad * 4 + i;
        const int gcol = bn + col0 + nt * 16 + r;
        P[(size_t)grow * N + gcol] = f2bf(acc[mt][nt][i]);
      }
}

// ---------------- Flash attention v13 (R12-verified: own-your-rows + LPT pairing) ----------------
#define ATTN_BODY(BUF, J0, RINK, RINV, ROUTK, ROUTV, DO_PF, DO_WR)                                 \
  {                                                                                                \
    __syncthreads();                                                                               \
    if (DO_PF) {                                                                                   \
      ROUTK = *(const short8*)&Kb[(size_t)((J0) + 64 + krow) * D_ + kg * 8];                       \
      ROUTV = *(const short8*)&VTb[(size_t)vrow * 2048 + (J0) + 64 + vg * 8];                      \
    }                                                                                              \
    f32x4 z[2][2];                                                                                 \
    __builtin_amdgcn_s_setprio(1);                                                                 \
    _Pragma("unroll") for (int kt = 0; kt < 2; ++kt) {                                             \
      const short8 kf0 = *(const short8*)&Ks[BUF][(kt * 16 + r) * 72 + quad * 8];                  \
      const short8 kf1 = *(const short8*)&Ks[BUF][(kt * 16 + r) * 72 + 32 + quad * 8];             \
      _Pragma("unroll") for (int f = 0; f < 2; ++f) {                                              \
        f32x4 zz = {};                                                                             \
        zz = __builtin_amdgcn_mfma_f32_16x16x32_bf16(qf[f][0], kf0, zz, 0, 0, 0);                  \
        zz = __builtin_amdgcn_mfma_f32_16x16x32_bf16(qf[f][1], kf1, zz, 0, 0, 0);                  \
        z[f][kt] = zz;                                                                             \
      }                                                                                            \
    }                                                                                              \
    __builtin_amdgcn_s_setprio(0);                                                                 \
    const bool masked = ((J0) + 31 > m0);                                                          \
    _Pragma("unroll") for (int f = 0; f < 2; ++f) _Pragma("unroll") for (int i = 0; i < 4; ++i) {  \
      const int qrow = m0 + f * 16 + quad * 4 + i;                                                 \
      float v0 = z[f][0][i];                                                                       \
      float v1 = z[f][1][i];                                                                       \
      if (masked) {                                                                                \
        if ((J0) + r > qrow) v0 = -128.f;                                                          \
        if ((J0) + 16 + r > qrow) v1 = -128.f;                                                     \
      }                                                                                            \
      *(uint32_t*)&Psw[(f * 16 + quad * 4 + i) * 40 + r * 2] = pack2bf(exp2f(v0), exp2f(v1));      \
    }                                                                                              \
    asm volatile("s_waitcnt lgkmcnt(0)" ::: "memory");                                             \
    short8 vf[4];                                                                                  \
    _Pragma("unroll") for (int nt = 0; nt < 4; ++nt)                                               \
        vf[nt] = *(const short8*)&Vs[BUF][(nt * 16 + r) * 40 + quad * 8];                          \
    __builtin_amdgcn_s_setprio(1);                                                                 \
    _Pragma("unroll") for (int f = 0; f < 2; ++f) {                                                \
      const short8 pf = *(const short8*)&Psw[(f * 16 + r) * 40 + quad * 8];                        \
      _Pragma("unroll") for (int nt = 0; nt < 4; ++nt)                                             \
          oacc[f][nt] = __builtin_amdgcn_mfma_f32_16x16x32_bf16(pf, vf[nt], oacc[f][nt], 0, 0, 0); \
      lacc[f] = __builtin_amdgcn_mfma_f32_16x16x32_bf16(pf, onesv, lacc[f], 0, 0, 0);              \
    }                                                                                              \
    __builtin_amdgcn_s_setprio(0);                                                                 \
    if (DO_WR) {                                                                                   \
      *(short8*)&Ks[(BUF) ^ 1][krow * 72 + kg * 8] = RINK;                                         \
      *(short8*)&Vs[(BUF) ^ 1][vrow * 40 + vg * 8] = RINV;                                         \
    }                                                                                              \
  }

__global__ __launch_bounds__(256, 2) void attn_k(const u16* __restrict__ Q,
                                                 const u16* __restrict__ Kx,
                                                 const u16* __restrict__ VT,
                                                 u16* __restrict__ O) {
  __shared__ alignas(16) u16 Ks[2][32 * 72];
  __shared__ alignas(16) u16 Vs[2][64 * 40];
  __shared__ alignas(16) u16 Ps[4][32 * 40];

  const int tid = threadIdx.x;
  const int wv = tid >> 6, lane = tid & 63;
  const int r = lane & 15, quad = lane >> 4;

  // LPT + same-CU pairing: i in [0,512). wave w: 0 = long (bx 15..8), 1 = short (bx 0..7).
  // Blocks i and i+256 share a CU (%8 XCD round-robin) and get complementary bx.
  const int i_ = blockIdx.x + 16 * blockIdx.y;
  const int w = i_ >> 8;
  const int j = i_ & 255;
  const int xcd = j & 7;
  const int u = j >> 3;                 // 0..31
  const int bh = xcd * 4 + (u >> 3);    // 4 bh per XCD (2MB KV in L2)
  const int s = u & 7;
  const int bx = w ? s : (15 - s);
  const int b = bh >> 4, hh = bh & 15;

  const int niter = (bx + 1) * 4;  // multiple of 4
  const int m0 = bx * 128 + wv * 32;
  const size_t base = (size_t)b * S_ * D_ + (size_t)hh * DH_;
  const u16* Qb = Q + base;
  const u16* Kb = Kx + base;
  const u16* VTb = VT + (size_t)bh * 64 * 2048;
  u16* Psw = &Ps[wv][0];

  short8 qf[2][2];
#pragma unroll
  for (int f = 0; f < 2; ++f) {
    qf[f][0] = *(const short8*)&Qb[(size_t)(m0 + f * 16 + r) * D_ + quad * 8];
    qf[f][1] = *(const short8*)&Qb[(size_t)(m0 + f * 16 + r) * D_ + 32 + quad * 8];
  }

  short8 onesv;
#pragma unroll
  for (int e = 0; e < 8; ++e) onesv[e] = (short)0x3F80;

  f32x4 oacc[2][4] = {};
  f32x4 lacc[2] = {};

  const int krow = tid >> 3, kg = tid & 7;
  const int vrow = tid >> 2, vg = tid & 3;

  // prologue: stage iter 0 into buf0; issue iter-1 loads into regA
  *(short8*)&Ks[0][krow * 72 + kg * 8] = *(const short8*)&Kb[(size_t)krow * D_ + kg * 8];
  *(short8*)&Vs[0][vrow * 40 + vg * 8] = *(const short8*)&VTb[(size_t)vrow * 2048 + vg * 8];
  short8 kA, vA, kB, vB;
  kA = *(const short8*)&Kb[(size_t)(32 + krow) * D_ + kg * 8];
  vA = *(const short8*)&VTb[(size_t)vrow * 2048 + 32 + vg * 8];

  for (int it = 0; it < niter; it += 2) {
    const int j0 = it * 32;
    ATTN_BODY(0, j0, kA, vA, kB, vB, (it + 2 < niter), true);
    ATTN_BODY(1, j0 + 32, kB, vB, kA, vA, (it + 3 < niter), (it + 2 < niter));
  }

  // epilogue: O = oacc / l, written directly (lacc holds the row sum in every lane).
#pragma unroll
  for (int f = 0; f < 2; ++f) {
#pragma unroll
    for (int i = 0; i < 4; ++i) {
      const int qrow = m0 + f * 16 + quad * 4 + i;
      const float linv = 1.0f / lacc[f][i];
#pragma unroll
      for (int nt = 0; nt < 4; ++nt)
        O[base + (size_t)qrow * D_ + nt * 16 + r] = f2bf(oacc[f][nt][i] * linv);
    }
  }
}

extern "C" void kernel_launch(void* const* d_in, const int* in_sizes, int n_in,
                              void* d_out, int out_size, void* d_ws, size_t ws_size,
                              hipStream_t stream) {
  (void)in_sizes; (void)n_in; (void)out_size; (void)ws_size;
  const float* x   = (const float*)d_in[0];
  const float* wq  = (const float*)d_in[1];
  const float* wk  = (const float*)d_in[2];
  const float* wvp = (const float*)d_in[3];
  const float* wo  = (const float*)d_in[4];
  const float* w1  = (const float*)d_in[5];
  const float* w2  = (const float*)d_in[6];
  const float* g1  = (const float*)d_in[7];
  const float* g2  = (const float*)d_in[8];
  float* out = (float*)d_out;  // x2 -> final output

  u16* ws = (u16*)d_ws;
  const size_t TD = (size_t)M_TOK * D_;  // 4M elems (8 MB)
  u16* h    = ws;            // slot0: h -> o -> t[0]
  u16* q    = ws + 1 * TD;   // slot1: q -> P0 -> t[1]
  u16* k    = ws + 2 * TD;   // slot2: k -> P1 -> t[2]
  u16* vt   = ws + 3 * TD;   // slot3: vt -> t[3]
  u16* h2   = ws + 4 * TD;   // slot4: h2 -> Q0
  u16* o    = h;             // attn writes o directly (h dead after QKV gemm)
  u16* t    = ws;            // FFN1 out spans slots 0..3
  u16* P0   = q;             // WO partials (q,k dead)
  u16* P1   = k;
  u16* Q0   = h2;            // FFN2 partials (h2 dead after FFN1)
  u16* wqkv = ws + 5 * TD;
  u16* wob  = wqkv + 3 * MEG;
  u16* w1b  = wob + 1 * MEG;
  u16* w2b  = w1b + 4 * MEG;
  u16* Q1   = w2b + 4 * MEG;  // tail: +8 MB (total ws ~73 MB)

  const dim3 blk(256);

  prep_k<<<PREP_CVT + M_TOK, blk, 0, stream>>>(wq, wk, wvp, wo, w1, w2, wqkv, wob, w1b, w2b,
                                               x, g1, h);
  gemm_bt_k<4><<<dim3(24, 32), blk, 0, stream>>>(h, wqkv, q, k, vt, 3072, 1024);
  attn_k<<<dim3(16, 32), blk, 0, stream>>>(q, k, vt, o);
  gemm_sk2_k<<<dim3(8, 32, 2), blk, 0, stream>>>(o, wob, P0, P1, 1024, 1024, 512);    // WO partials
  rmsnorm_wo_k<<<M_TOK, blk, 0, stream>>>(P0, P1, x, g2, out, h2);                    // x2 + h2 fused
  gemm_bt_k<2><<<dim3(32, 32), blk, 0, stream>>>(h2, w1b, t, nullptr, nullptr, 4096, 1024);
  gemm_sk2_k<<<dim3(8, 32, 2), blk, 0, stream>>>(t, w2b, Q0, Q1, 1024, 4096, 2048);   // FFN2 partials
  ffn2_red_k<<<4096, blk, 0, stream>>>(Q0, Q1, out);                                  // out = Q0+Q1+x2
}